// Round 5
// baseline (799.358 us; speedup 1.0000x reference)
//
#include <hip/hip_runtime.h>

// ---------------------------------------------------------------------------
// AdderNet decoder, R5: u16 fixed-point quantization + v_sad_u32 (fused
// |a-b|+acc = 1 VALU/tap). Activations live padded (N,C,H+2,W+4) as u16,
// q(v) = round((v+8)*4096). Pad cells = q(0) = 32768 (border-fill kernel).
// ci-split adders accumulate exact u32 partial sums via global atomics into
// a shared accumulator region U; combine kernels read U, restore zeros,
// apply -sum/4096 -> relu/bn -> requantize (or write f32 for unpool/out).
// Quantized weights prepared on-device each launch (deterministic).
// ---------------------------------------------------------------------------

#define QS 4096.0f
#define QOFF 8.0f
#define Q0 32768  // q(0)

__device__ __forceinline__ unsigned sad32(unsigned a, unsigned b, unsigned c) {
    unsigned d;
    asm("v_sad_u32 %0, %1, %2, %3" : "=v"(d) : "v"(a), "v"(b), "v"(c));
    return d;
}

__device__ __forceinline__ unsigned short qz(float v) {
    int q = (int)roundf((v + QOFF) * QS);
    q = q < 0 ? 0 : (q > 65535 ? 65535 : q);
    return (unsigned short)q;
}

// ---- weight prep: f32 [co][ci][3][3] -> quantized u32, layout
// [cog][ci][j][k] (j in co-group of size g) per layer, concatenated.
struct PrepArgs {
    const float* src[8];
    int start[9];    // prefix sums of co*ci*9 per layer; start[8]=total
    int cin[8];
    int g[8];
    int dstoff[8];   // u32 offset into WQ
};

__global__ __launch_bounds__(256) void prep_w_k(PrepArgs a, unsigned* __restrict__ dst)
{
    int i = blockIdx.x * 256 + threadIdx.x;
    if (i >= a.start[8]) return;
    int seg = 0;
#pragma unroll
    for (int s = 1; s < 8; ++s) if (i >= a.start[s]) seg = s;
    int local = i - a.start[seg];
    int cin9 = a.cin[seg] * 9;
    int co  = local / cin9;
    int rem = local - co * cin9;
    int ci  = rem / 9;
    int k   = rem - ci * 9;
    int g   = a.g[seg];
    int cog = co / g, j = co - cog * g;
    float w = a.src[seg][local];
    int q = (int)roundf((w + QOFF) * QS);
    q = q < 0 ? 0 : (q > 65535 ? 65535 : q);
    dst[a.dstoff[seg] + ((cog * a.cin[seg] + ci) * g + j) * 9 + k] = (unsigned)q;
}

// ---- border fill: write Q0 to rows 0,H+1 (full wpad) and cols 0,W+1.
struct BorderArgs {
    unsigned short* buf[6];
    int NC[6], H[6], W[6];
    int start[7];
};

__global__ __launch_bounds__(256) void border_k(BorderArgs a)
{
    int i = blockIdx.x * 256 + threadIdx.x;
    if (i >= a.start[6]) return;
    int seg = 0;
#pragma unroll
    for (int s = 1; s < 6; ++s) if (i >= a.start[s]) seg = s;
    int local = i - a.start[seg];
    int H = a.H[seg], W = a.W[seg];
    int wpad = W + 4;
    int rowcells = a.NC[seg] * 2 * wpad;
    unsigned short* b = a.buf[seg];
    if (local < rowcells) {
        int nc = local / (2 * wpad);
        int r2 = local - nc * (2 * wpad);
        int row = (r2 < wpad) ? 0 : (H + 1);
        int col = (r2 < wpad) ? r2 : (r2 - wpad);
        b[((size_t)nc * (H + 2) + row) * wpad + col] = Q0;
    } else {
        int i2 = local - rowcells;
        int nc = i2 / (2 * H);
        int rr = i2 - nc * (2 * H);
        int row = 1 + (rr >> 1);
        int col = (rr & 1) ? (W + 1) : 0;
        b[((size_t)nc * (H + 2) + row) * wpad + col] = Q0;
    }
}

// ---- input pad+quant: f32 (4,128,32,32) -> u16 padded interior
__global__ __launch_bounds__(256) void pad_quant_k(
    const float* __restrict__ in, unsigned short* __restrict__ out)
{
    int i = blockIdx.x * 256 + threadIdx.x;  // grid exact: 524288
    int w_ = i & 31;
    int t  = i >> 5;
    int h  = t & 31;
    int nc = t >> 5;
    out[((size_t)nc * 34 + (h + 1)) * 36 + (w_ + 1)] = qz(in[i]);
}

// ---- unpool + relu + bn + quantize -> u16 padded
__global__ __launch_bounds__(256) void unpool_q_k(
    const float* __restrict__ in, const int* __restrict__ locs,
    const float* __restrict__ bw, const float* __restrict__ bb,
    unsigned short* __restrict__ out, int C, int H, int W)
{
    int i = blockIdx.x * 256 + threadIdx.x;  // grid exact: N*C*H*W
    int w_ = i % W;
    int t  = i / W;
    int h  = t % H; t /= H;
    int c  = t % C;
    int n  = t / C;
    float v  = in[i];
    int   id = locs[i];
    int Wo = 2 * W;
    int ho = id / Wo, wo = id % Wo;
    float scale = bw[c], bias = bb[c];
    unsigned short val = qz(fmaxf(v, 0.f) * scale + bias);
    unsigned short bq  = qz(bias);
    int wpad = Wo + 4;
    unsigned short* ob = out + (size_t)(n * C + c) * (2 * H + 2) * wpad;
    int h0 = 2 * h, w0 = 2 * w_;
#pragma unroll
    for (int dy = 0; dy < 2; ++dy)
#pragma unroll
        for (int dx = 0; dx < 2; ++dx) {
            ob[(size_t)(h0 + dy + 1) * wpad + (w0 + dx + 1)] =
                (h0 + dy == ho && w0 + dx == wo) ? val : bq;
        }
}

// ---- combine: read u32 sums, restore zeros, convert, (relu+bn+quant -> u16
// padded) or (f32 flat). Grid exact over cells.
template <bool BNQ, bool ZR>
__global__ __launch_bounds__(256) void combine_k(
    unsigned* __restrict__ U,
    const float* __restrict__ bw, const float* __restrict__ bb,
    unsigned short* __restrict__ outq, float* __restrict__ outf,
    int C, int H, int W)
{
    int i = blockIdx.x * 256 + threadIdx.x;
    unsigned sum = U[i];
    if constexpr (ZR) U[i] = 0u;
    float h = -(float)sum * (1.0f / QS);
    if constexpr (BNQ) {
        int w_ = i % W;
        int t  = i / W;
        int hh = t % H; t /= H;
        int c  = t % C;
        int n  = t / C;
        float a = fmaxf(h, 0.f) * bw[c] + bb[c];
        int wpad = W + 4;
        outq[((size_t)(n * C + c) * (H + 2) + (hh + 1)) * wpad + (w_ + 1)] = qz(a);
    } else {
        outf[i] = h;
    }
}

// ---- the SAD adder. u16 padded input, LDS-staged quantized weights,
// G output channels x 4-px strip per thread, ci-split with atomic u32 acc.
template <int CIN, int CHUNK, int G>
__global__ __launch_bounds__(256, 4) void adder_sad(
    const unsigned short* __restrict__ xin, const unsigned* __restrict__ wq,
    unsigned* __restrict__ U,
    int H, int W, int COUT, int NCOG, int SPB, int S)
{
    const int wpad = W + 4;
    const int chst = (H + 2) * wpad;
    int b = blockIdx.x;
    const int s   = b % S;    b /= S;
    const int sb  = b % SPB;  b /= SPB;
    const int cog = b % NCOG;
    const int n   = b / NCOG;
    const int ci0 = s * CHUNK;

    const int t   = sb * 256 + (int)threadIdx.x;
    const int spr = W >> 2;              // strips per row (W/4)
    const int r   = t / spr;
    const int c0  = (t - r * spr) * 4;   // padded u16 col of window start (even)

    // stage this block's weights into LDS: [cc][j] stride 12 u32 (16B-aligned)
    __shared__ unsigned lw[CHUNK * G * 12];
    {
        const int total = CHUNK * G * 9;
        const int gbase = (cog * CIN + ci0) * G * 9;
        for (int i = threadIdx.x; i < total; i += 256) {
            int cj = i / 9, k = i - cj * 9;
            lw[cj * 12 + k] = wq[gbase + i];
        }
    }
    __syncthreads();

    unsigned acc[G][4];
#pragma unroll
    for (int j = 0; j < G; ++j)
#pragma unroll
        for (int p = 0; p < 4; ++p) acc[j][p] = 0u;

    const unsigned short* xp = xin + ((size_t)(n * CIN + ci0) * chst + r * wpad + c0);

#pragma unroll 2
    for (int cc = 0; cc < CHUNK; ++cc) {
        const unsigned* r0 = (const unsigned*)xp;
        const unsigned* r1 = (const unsigned*)(xp + wpad);
        const unsigned* r2 = (const unsigned*)(xp + 2 * wpad);
        unsigned a0 = r0[0], a1 = r0[1], a2 = r0[2];
        unsigned b0 = r1[0], b1 = r1[1], b2 = r1[2];
        unsigned c0w = r2[0], c1 = r2[1], c2 = r2[2];
        unsigned e[3][6];
        e[0][0] = a0 & 0xffffu; e[0][1] = a0 >> 16; e[0][2] = a1 & 0xffffu;
        e[0][3] = a1 >> 16;     e[0][4] = a2 & 0xffffu; e[0][5] = a2 >> 16;
        e[1][0] = b0 & 0xffffu; e[1][1] = b0 >> 16; e[1][2] = b1 & 0xffffu;
        e[1][3] = b1 >> 16;     e[1][4] = b2 & 0xffffu; e[1][5] = b2 >> 16;
        e[2][0] = c0w & 0xffffu; e[2][1] = c0w >> 16; e[2][2] = c1 & 0xffffu;
        e[2][3] = c1 >> 16;     e[2][4] = c2 & 0xffffu; e[2][5] = c2 >> 16;

        const unsigned* wb = &lw[cc * G * 12];
#pragma unroll
        for (int j = 0; j < G; ++j) {
            unsigned wv[9];
#pragma unroll
            for (int k = 0; k < 9; ++k) wv[k] = wb[j * 12 + k];
#pragma unroll
            for (int di = 0; di < 3; ++di)
#pragma unroll
                for (int dj = 0; dj < 3; ++dj) {
#pragma unroll
                    for (int p = 0; p < 4; ++p)
                        acc[j][p] = sad32(e[di][p + dj], wv[di * 3 + dj], acc[j][p]);
                }
        }
        xp += chst;
    }

    const int obase = ((n * COUT + cog * G) * H + r) * W + c0;
#pragma unroll
    for (int j = 0; j < G; ++j)
#pragma unroll
        for (int p = 0; p < 4; ++p)
            atomicAdd(&U[obase + j * H * W + p], acc[j][p]);
}

// ---------------------------------------------------------------------------

extern "C" void kernel_launch(void* const* d_in, const int* in_sizes, int n_in,
                              void* d_out, int out_size, void* d_ws, size_t ws_size,
                              hipStream_t stream)
{
    const float* x      = (const float*)d_in[0];
    const int*   locs13 = (const int*)d_in[3];
    const int*   locs6  = (const int*)d_in[4];
    const float* w3  = (const float*)d_in[5];
    const float* w6  = (const float*)d_in[6];
    const float* w9  = (const float*)d_in[7];
    const float* w12 = (const float*)d_in[8];
    const float* w16 = (const float*)d_in[9];
    const float* w19 = (const float*)d_in[10];
    const float* w23 = (const float*)d_in[11];
    const float* w26 = (const float*)d_in[12];
    const float* bn5w  = (const float*)d_in[13], *bn5b  = (const float*)d_in[14];
    const float* bn8w  = (const float*)d_in[15], *bn8b  = (const float*)d_in[16];
    const float* bn11w = (const float*)d_in[17], *bn11b = (const float*)d_in[18];
    const float* bn15w = (const float*)d_in[19], *bn15b = (const float*)d_in[20];
    const float* bn18w = (const float*)d_in[21], *bn18b = (const float*)d_in[22];
    const float* bn22w = (const float*)d_in[23], *bn22b = (const float*)d_in[24];
    const float* bn25w = (const float*)d_in[25], *bn25b = (const float*)d_in[26];

    char* ws = (char*)d_ws;
    // layout (bytes)
    unsigned*       U  = (unsigned*)(ws + 0);              // 8,388,608 B (2M cells max, L23)
    unsigned short* A0 = (unsigned short*)(ws + 8388608);  // 4x128x34x36 u16
    unsigned short* A1 = (unsigned short*)(ws + 9641984);
    unsigned short* A3 = (unsigned short*)(ws + 10895360); // 4x64x66x68
    unsigned short* A4 = (unsigned short*)(ws + 13193216);
    unsigned short* A5 = (unsigned short*)(ws + 15491072); // 4x32x130x132
    unsigned short* A6 = (unsigned short*)(ws + 19884032);
    float*          F1 = (float*)(ws + 24276992);          // 4x64x32x32 f32
    float*          F2 = (float*)(ws + 25325568);          // 4x32x64x64 f32
    unsigned*       WQ = (unsigned*)(ws + 27422720);       // 581472 u32

    // zero the atomic accumulator region (combine kernels keep it zeroed)
    hipMemsetAsync(U, 0, 8388608, stream);

    // quantized weight prep (all 8 layers, one kernel)
    PrepArgs pa;
    pa.src[0] = w3;  pa.src[1] = w6;  pa.src[2] = w9;  pa.src[3] = w12;
    pa.src[4] = w16; pa.src[5] = w19; pa.src[6] = w23; pa.src[7] = w26;
    int counts[8] = {147456, 147456, 147456, 73728, 36864, 18432, 9216, 864};
    int cins[8]   = {128, 128, 128, 128, 64, 64, 32, 32};
    int gs[8]     = {8, 8, 8, 8, 8, 8, 8, 3};
    int acc_ = 0;
    for (int i = 0; i < 8; ++i) { pa.start[i] = acc_; pa.dstoff[i] = acc_; pa.cin[i] = cins[i]; pa.g[i] = gs[i]; acc_ += counts[i]; }
    pa.start[8] = acc_;  // 581472
    prep_w_k<<<(acc_ + 255) / 256, 256, 0, stream>>>(pa, WQ);

    // border fill on all padded activation buffers
    BorderArgs ba;
    unsigned short* bufs[6] = {A0, A1, A3, A4, A5, A6};
    int ncs[6] = {512, 512, 256, 256, 128, 128};
    int hs[6]  = {32, 32, 64, 64, 128, 128};
    int wsz[6] = {32, 32, 64, 64, 128, 128};
    int bacc = 0;
    for (int i = 0; i < 6; ++i) {
        ba.buf[i] = bufs[i]; ba.NC[i] = ncs[i]; ba.H[i] = hs[i]; ba.W[i] = wsz[i];
        ba.start[i] = bacc;
        bacc += ncs[i] * (2 * (wsz[i] + 4) + 2 * hs[i]);
    }
    ba.start[6] = bacc;  // 407552
    border_k<<<(bacc + 255) / 256, 256, 0, stream>>>(ba);

    // input -> A0
    pad_quant_k<<<2048, 256, 0, stream>>>(x, A0);

    // L3: 128->128 @32x32. NCOG=16,SPB=1,S=16,CHUNK=8 -> 1024 blocks
    adder_sad<128, 8, 8><<<1024, 256, 0, stream>>>(A0, WQ + 0, U, 32, 32, 128, 16, 1, 16);
    combine_k<true, true><<<2048, 256, 0, stream>>>(U, bn5w, bn5b, A1, nullptr, 128, 32, 32);

    // L6
    adder_sad<128, 8, 8><<<1024, 256, 0, stream>>>(A1, WQ + 147456, U, 32, 32, 128, 16, 1, 16);
    combine_k<true, true><<<2048, 256, 0, stream>>>(U, bn8w, bn8b, A0, nullptr, 128, 32, 32);

    // L9
    adder_sad<128, 8, 8><<<1024, 256, 0, stream>>>(A0, WQ + 294912, U, 32, 32, 128, 16, 1, 16);
    combine_k<true, true><<<2048, 256, 0, stream>>>(U, bn11w, bn11b, A1, nullptr, 128, 32, 32);

    // L12: 128->64 @32x32. NCOG=8,SPB=1,S=32,CHUNK=4 -> 1024 blocks
    adder_sad<128, 4, 8><<<1024, 256, 0, stream>>>(A1, WQ + 442368, U, 32, 32, 64, 8, 1, 32);
    combine_k<false, true><<<1024, 256, 0, stream>>>(U, nullptr, nullptr, nullptr, F1, 64, 32, 32);

    // unpool13 + relu + bn15 -> A3
    unpool_q_k<<<1024, 256, 0, stream>>>(F1, locs13, bn15w, bn15b, A3, 64, 32, 32);

    // L16: 64->64 @64x64. NCOG=8,SPB=4,S=8,CHUNK=8 -> 1024 blocks
    adder_sad<64, 8, 8><<<1024, 256, 0, stream>>>(A3, WQ + 516096, U, 64, 64, 64, 8, 4, 8);
    combine_k<true, true><<<4096, 256, 0, stream>>>(U, bn18w, bn18b, A4, nullptr, 64, 64, 64);

    // L19: 64->32 @64x64. NCOG=4,SPB=4,S=16,CHUNK=4 -> 1024 blocks
    adder_sad<64, 4, 8><<<1024, 256, 0, stream>>>(A4, WQ + 552960, U, 64, 64, 32, 4, 4, 16);
    combine_k<false, true><<<2048, 256, 0, stream>>>(U, nullptr, nullptr, nullptr, F2, 32, 64, 64);

    // unpool6 + relu + bn22 -> A5
    unpool_q_k<<<2048, 256, 0, stream>>>(F2, locs6, bn22w, bn22b, A5, 32, 64, 64);

    // L23: 32->32 @128x128. NCOG=4,SPB=16,S=4,CHUNK=8 -> 1024 blocks
    adder_sad<32, 8, 8><<<1024, 256, 0, stream>>>(A5, WQ + 571392, U, 128, 128, 32, 4, 16, 4);
    combine_k<true, true><<<8192, 256, 0, stream>>>(U, bn25w, bn25b, A6, nullptr, 32, 128, 128);

    // L26: 32->3 @128x128 -> d_out f32. G=3. NCOG=1,SPB=16,S=16,CHUNK=2 -> 1024
    adder_sad<32, 2, 3><<<1024, 256, 0, stream>>>(A6, WQ + 580608, U, 128, 128, 3, 1, 16, 16);
    combine_k<false, false><<<768, 256, 0, stream>>>(U, nullptr, nullptr, nullptr, (float*)d_out, 3, 128, 128);
}

// Round 6
// 10.506 us; speedup vs baseline: 76.0873x; 76.0873x over previous
//
#include <hip/hip_runtime.h>

// ---------------------------------------------------------------------------
// AdderDeconv — exact algebraic reduction.
//
// Identity: adder_l1(x,w) = -sum |...| <= 0 for every finite input, and the
// reference applies bn_t(relu(h),w,b) = relu(h)*w + b after every adder (and
// after each unpool, whose scatter output is also <= 0 everywhere). Hence
// relu(...) == 0 identically and every post-BN activation equals its BN bias
// exactly, per channel, at every pixel, for ALL finite inputs. By induction
// the entire network output is:
//
//   out[n,co,y,x] = - sum_ci sum_{di,dj}  ( tap in-bounds ?
//                        |bn25_b[ci] - w26[co,ci,di,dj]|
//                      : |w26[co,ci,di,dj]| )            (independent of n, x)
//
// Only bn25_b and w26 are live inputs. We compute the 2*3*9 tap-sums from the
// device inputs in each block's LDS (54 threads x 32-term sums), then paint
// the 4x3x128x128 output with the 9-tap border-class select.
// ---------------------------------------------------------------------------

__global__ __launch_bounds__(256) void final_k(
    const float* __restrict__ bn25_b,   // (32,)
    const float* __restrict__ w26,      // (3,32,3,3)
    float* __restrict__ out)            // (4,3,128,128)
{
    // TU[0][co][d] = sum_ci |bn25_b[ci] - w26[co,ci,d]|   (in-bounds tap)
    // TU[1][co][d] = sum_ci |w26[co,ci,d]|                (padding tap)
    __shared__ float TU[2][3][9];
    const int t = threadIdx.x;
    if (t < 54) {
        const int which = t / 27;
        const int k  = t % 27;
        const int co = k / 9;
        const int d  = k % 9;
        float s = 0.f;
#pragma unroll 4
        for (int ci = 0; ci < 32; ++ci) {
            const float w = w26[(co * 32 + ci) * 9 + d];
            s += which ? fabsf(w) : fabsf(bn25_b[ci] - w);
        }
        TU[which][co][d] = s;
    }
    __syncthreads();

    const int i = blockIdx.x * 256 + t;       // grid exact: 768*256 = 196608
    const int x  = i & 127;
    const int y  = (i >> 7) & 127;
    const int co = (i >> 14) % 3;             // n = i >> 14 / 3 (output same for all n)

    float s = 0.f;
#pragma unroll
    for (int di = 0; di < 3; ++di) {
        const bool yin = (unsigned)(y + di - 1) < 128u;
#pragma unroll
        for (int dj = 0; dj < 3; ++dj) {
            const bool inb = yin && ((unsigned)(x + dj - 1) < 128u);
            s += TU[inb ? 0 : 1][co][di * 3 + dj];
        }
    }
    out[i] = -s;
}

// ---------------------------------------------------------------------------

extern "C" void kernel_launch(void* const* d_in, const int* in_sizes, int n_in,
                              void* d_out, int out_size, void* d_ws, size_t ws_size,
                              hipStream_t stream)
{
    const float* w26    = (const float*)d_in[12];
    const float* bn25_b = (const float*)d_in[26];

    final_k<<<768, 256, 0, stream>>>(bn25_b, w26, (float*)d_out);
}